// Round 7
// baseline (55.206 us; speedup 1.0000x reference)
//
#include <hip/hip_runtime.h>

#define N2   8192
#define DDIM 256
#define NTRI 2080 // 64*65/2 upper-triangle 128x128 blocks

static constexpr float INV_T = 1.0f / 0.07f;

using f32x4 = __attribute__((ext_vector_type(4))) float;
typedef unsigned int  u32;
typedef long long     i64;

#define GL2LDS(gp, lp) __builtin_amdgcn_global_load_lds( \
    (const __attribute__((address_space(1))) void*)(gp), \
    (__attribute__((address_space(3))) void*)(lp), 16, 0, 0)

// ---------- kernel 1: normalize rows, f32 -> fp8 e4m3 (OCP) ----------
__global__ void ntx_norm(const float* __restrict__ z1, const float* __restrict__ z2,
                         unsigned char* __restrict__ zn)
{
    const int w    = threadIdx.x >> 6;
    const int lane = threadIdx.x & 63;
    const int row  = blockIdx.x * 4 + w;

    const float* src = (row < 4096) ? (z1 + (size_t)row * DDIM)
                                    : (z2 + (size_t)(row - 4096) * DDIM);
    float4 v = *(const float4*)(src + lane * 4);
    float ss = v.x * v.x + v.y * v.y + v.z * v.z + v.w * v.w;
    #pragma unroll
    for (int m = 1; m < 64; m <<= 1) ss += __shfl_xor(ss, m, 64);

    float inv = 1.0f / fmaxf(sqrtf(ss), 1e-8f);

    u32 p = __builtin_amdgcn_cvt_pk_fp8_f32(v.x * inv, v.y * inv, 0u, false);
    p     = __builtin_amdgcn_cvt_pk_fp8_f32(v.z * inv, v.w * inv, p, true);
    ((u32*)zn)[(size_t)row * 64 + lane] = p;
}

// ---------- kernel 2: upper-triangle sim blocks, fp8 MFMA ----------
// 128x128 tile, 4 waves (2x2), BK=128 (2 K-tiles, 3 barriers), 32 KB LDS,
// global_load_lds width-16: linear LDS dest + inverse-swizzled global source,
// 16B-granule XOR swizzle ((row&3)<<4) on ds_read (rule-21 pair).
__global__ __launch_bounds__(256, 3)
void ntx_gemm(const unsigned char* __restrict__ zn, float* __restrict__ partials,
              float* __restrict__ pos)
{
    __shared__ unsigned char lsA[16384];   // 128 rows x 128 B (BK=128 fp8)
    __shared__ unsigned char lsB[16384];

    const int tid  = threadIdx.x;
    const int lane = tid & 63;
    const int w    = tid >> 6;       // 0..3
    const int wr   = w >> 1;         // 0..1
    const int wc   = w & 1;          // 0..1

    // triangle decode: blockIdx.x -> (br, bc), br <= bc
    const int t = (int)blockIdx.x;
    int br = (int)((129.0f - sqrtf(16641.0f - 8.0f * (float)t)) * 0.5f);
    while ((br + 1) * (129 - (br + 1)) / 2 <= t) ++br;
    while (br * (129 - br) / 2 > t) --br;
    const int bc = br + (t - br * (129 - br) / 2);

    const int fr  = lane & 15;               // fragment row/col
    const int kl  = lane >> 4;               // k-group 0..3
    const int swz = (fr & 3) << 4;           // read-side swizzle (16B granule)

    // staging: issue i covers rows i*32 + w*8 + (lane>>3); wave-uniform LDS base,
    // inverse-swizzled global source column (involution with read swizzle)
    auto stage = [&](int kt) {
        #pragma unroll
        for (int i = 0; i < 4; ++i) {
            const int row = i * 32 + w * 8 + (lane >> 3);
            const int sc  = ((lane & 7) * 16) ^ ((row & 3) << 4);
            GL2LDS((const char*)zn + (size_t)(br * 128 + row) * 256 + kt * 128 + sc,
                   (unsigned char*)lsA + i * 4096 + w * 1024);
            GL2LDS((const char*)zn + (size_t)(bc * 128 + row) * 256 + kt * 128 + sc,
                   (unsigned char*)lsB + i * 4096 + w * 1024);
        }
    };

    f32x4 acc[4][4] = {};

    auto compute = [&]() {
        #pragma unroll
        for (int ks = 0; ks < 4; ++ks) {           // K=32 per MFMA, BK=128
            const int kb = ks * 32 + kl * 8;
            i64 af[4], bv[4];
            #pragma unroll
            for (int mf = 0; mf < 4; ++mf) {
                const int r = wr * 64 + mf * 16 + fr;
                af[mf] = *(const i64*)((const char*)lsA + r * 128 + (kb ^ swz));
            }
            #pragma unroll
            for (int nf = 0; nf < 4; ++nf) {
                const int c = wc * 64 + nf * 16 + fr;
                bv[nf] = *(const i64*)((const char*)lsB + c * 128 + (kb ^ swz));
            }
            __builtin_amdgcn_s_setprio(1);
            #pragma unroll
            for (int mf = 0; mf < 4; ++mf)
                #pragma unroll
                for (int nf = 0; nf < 4; ++nf)
                    acc[mf][nf] = __builtin_amdgcn_mfma_f32_16x16x32_fp8_fp8(
                        af[mf], bv[nf], acc[mf][nf], 0, 0, 0);
            __builtin_amdgcn_s_setprio(0);
        }
    };

    stage(0);
    __syncthreads();
    compute();
    __syncthreads();
    stage(1);
    __syncthreads();
    compute();

    // ---- epilogue (R2-proven) ----
    // e = exp((dot-1)/T), diag masked. Row sums -> partials[row][2*bc+wc];
    // off-diag blocks add transpose col sums -> partials[col][2*br+wr].
    const bool offdiag = (br != bc);
    const bool posblk  = (bc == br + 32);
    float colsum[4] = {0.f, 0.f, 0.f, 0.f};

    #pragma unroll
    for (int mf = 0; mf < 4; ++mf) {
        float rs[4] = {0.f, 0.f, 0.f, 0.f};
        const int rowq = br * 128 + wr * 64 + mf * 16 + kl * 4;
        #pragma unroll
        for (int nf = 0; nf < 4; ++nf) {
            const int col = bc * 128 + wc * 64 + nf * 16 + fr;
            f32x4 a = acc[mf][nf];
            #pragma unroll
            for (int j = 0; j < 4; ++j) {
                float e = (rowq + j == col) ? 0.f : __expf((a[j] - 1.0f) * INV_T);
                rs[j]      += e;
                colsum[nf] += e;
                if (posblk && (rowq + j + 4096 == col)) {
                    pos[rowq + j] = a[j];
                    pos[col]      = a[j];
                }
            }
        }
        #pragma unroll
        for (int m = 1; m < 16; m <<= 1) {
            #pragma unroll
            for (int j = 0; j < 4; ++j) rs[j] += __shfl_xor(rs[j], m, 64);
        }
        if (fr == 0) {
            float* p = partials + (size_t)rowq * 128 + bc * 2 + wc;
            p[0]   = rs[0];
            p[128] = rs[1];
            p[256] = rs[2];
            p[384] = rs[3];
        }
    }

    if (offdiag) {
        #pragma unroll
        for (int m = 16; m < 64; m <<= 1) {
            #pragma unroll
            for (int nf = 0; nf < 4; ++nf) colsum[nf] += __shfl_xor(colsum[nf], m, 64);
        }
        if (kl == 0) {
            #pragma unroll
            for (int nf = 0; nf < 4; ++nf) {
                const int col = bc * 128 + wc * 64 + nf * 16 + fr;
                partials[(size_t)col * 128 + br * 2 + wr] = colsum[nf];
            }
        }
    }
}

// ---------- kernel 3: fused loss + deterministic mean (last-block pattern) ----------
// 64 blocks x 1024 threads; block handles 128 rows; last block (atomic counter)
// reduces the 64 block sums in a fixed shfl tree -> deterministic.
__global__ void ntx_loss(const float* __restrict__ partials, const float* __restrict__ pos,
                         float* __restrict__ bsums, u32* __restrict__ counter,
                         float* __restrict__ out)
{
    __shared__ float sm[16];
    __shared__ u32 flag;
    const int tid  = threadIdx.x;
    const int lane = tid & 63;
    const int w    = tid >> 6;       // 0..15

    float a = 0.f;
    #pragma unroll
    for (int i = 0; i < 8; ++i) {
        const int row = blockIdx.x * 128 + w * 8 + i;
        float S = partials[(size_t)row * 128 + lane] + partials[(size_t)row * 128 + 64 + lane];
        #pragma unroll
        for (int m = 1; m < 64; m <<= 1) S += __shfl_xor(S, m, 64);
        if (lane == 0) a += __logf(S) + INV_T - pos[row] * INV_T;
    }
    if (lane == 0) sm[w] = a;
    __syncthreads();

    if (tid == 0) {
        float b = 0.f;
        #pragma unroll
        for (int i = 0; i < 16; ++i) b += sm[i];
        bsums[blockIdx.x] = b;
        __threadfence();                       // release block sum
        u32 old = atomicAdd(counter, 1u);
        flag = (old == 63u) ? 1u : 0u;
    }
    __syncthreads();

    if (flag && w == 0) {                      // last block's wave 0
        __threadfence();                       // acquire all block sums
        float v = bsums[lane];
        #pragma unroll
        for (int m = 1; m < 64; m <<= 1) v += __shfl_xor(v, m, 64);
        if (lane == 0) out[0] = v * (1.0f / (float)N2);
    }
}

extern "C" void kernel_launch(void* const* d_in, const int* in_sizes, int n_in,
                              void* d_out, int out_size, void* d_ws, size_t ws_size,
                              hipStream_t stream)
{
    const float* z1 = (const float*)d_in[0];
    const float* z2 = (const float*)d_in[1];
    float* out = (float*)d_out;

    // workspace layout
    unsigned char* zn       = (unsigned char*)d_ws;                 // 8192*256  = 2 MB
    float*         partials = (float*)((char*)d_ws + (2u << 20));   // 8192*128*4 = 4 MB
    float*         pos      = (float*)((char*)d_ws + (6u << 20));   // 32 KB
    float*         bsums    = pos + N2;                             // 256 B
    u32*           counter  = (u32*)(bsums + 64);                   // 4 B

    hipMemsetAsync(counter, 0, 4, stream);
    ntx_norm<<<N2 / 4, 256, 0, stream>>>(z1, z2, zn);
    ntx_gemm<<<NTRI, 256, 0, stream>>>(zn, partials, pos);
    ntx_loss<<<64, 1024, 0, stream>>>(partials, pos, bsums, counter, out);
}

// Round 8
// 48.140 us; speedup vs baseline: 1.1468x; 1.1468x over previous
//
#include <hip/hip_runtime.h>

#define N2   8192
#define NTRI 2080 // 64*65/2 upper-triangle 128x128 blocks

static constexpr float INV_T = 1.0f / 0.07f;

using f32x4 = __attribute__((ext_vector_type(4))) float;
using i32x4 = __attribute__((ext_vector_type(4))) int;
using i32x8 = __attribute__((ext_vector_type(8))) int;
typedef unsigned int u32;

#define GL2LDS(gp, lp) __builtin_amdgcn_global_load_lds( \
    (const __attribute__((address_space(1))) void*)(gp), \
    (__attribute__((address_space(3))) void*)(lp), 16, 0, 0)

#define SCALE1 0x7F7F7F7F   // E8M0 127 = 2^0 in every byte -> scale 1.0

// ---------- kernel 1: normalize rows, f32 -> fp8 e4m3 (OCP) ----------
__global__ void ntx_norm(const float* __restrict__ z1, const float* __restrict__ z2,
                         unsigned char* __restrict__ zn)
{
    const int w    = threadIdx.x >> 6;
    const int lane = threadIdx.x & 63;
    const int row  = blockIdx.x * 4 + w;

    const float* src = (row < 4096) ? (z1 + (size_t)row * 256)
                                    : (z2 + (size_t)(row - 4096) * 256);
    float4 v = *(const float4*)(src + lane * 4);
    float ss = v.x * v.x + v.y * v.y + v.z * v.z + v.w * v.w;
    #pragma unroll
    for (int m = 1; m < 64; m <<= 1) ss += __shfl_xor(ss, m, 64);

    float inv = 1.0f / fmaxf(sqrtf(ss), 1e-8f);

    u32 p = __builtin_amdgcn_cvt_pk_fp8_f32(v.x * inv, v.y * inv, 0u, false);
    p     = __builtin_amdgcn_cvt_pk_fp8_f32(v.z * inv, v.w * inv, p, true);
    ((u32*)zn)[(size_t)row * 64 + lane] = p;
}

// ---------- kernel 2: upper-triangle sim blocks, MX-scaled fp8 MFMA (K=128) ----------
// 128x128 tile, 4 waves (2x2), BK=128 fp8 = 128 B/row, 32 KB LDS single-buffer
// (~3 blocks/CU). global_load_lds width-16: linear LDS dest + inverse-swizzled
// global source ((row&7)<<4), XOR-swizzled b128 ds_read (rule-21 pair).
// One mfma_scale_f32_16x16x128_f8f6f4 per fragment pair per K-tile, scale=1.
__global__ __launch_bounds__(256, 3)
void ntx_gemm(const unsigned char* __restrict__ zn, float* __restrict__ partials,
              float* __restrict__ pos)
{
    __shared__ __align__(16) unsigned char lsA[16384];   // 128 rows x 128 B
    __shared__ __align__(16) unsigned char lsB[16384];

    const int tid  = threadIdx.x;
    const int lane = tid & 63;
    const int w    = tid >> 6;       // 0..3
    const int wr   = w >> 1;         // 0..1
    const int wc   = w & 1;          // 0..1

    // triangle decode: blockIdx.x -> (br, bc), br <= bc
    const int t = (int)blockIdx.x;
    int br = (int)((129.0f - sqrtf(16641.0f - 8.0f * (float)t)) * 0.5f);
    while ((br + 1) * (129 - (br + 1)) / 2 <= t) ++br;
    while (br * (129 - br) / 2 > t) --br;
    const int bc = br + (t - br * (129 - br) / 2);

    const int fr  = lane & 15;               // fragment row/col
    const int kl  = lane >> 4;               // k-group 0..3 (32 B each)
    const int swz = (fr & 7) << 4;           // read-side swizzle (8-bank spread)

    // staging: issue i covers rows i*32 + w*8 + (lane>>3); wave-uniform LDS base,
    // inverse-swizzled global source column (involution with read swizzle)
    const int srow = w * 8 + (lane >> 3);
    const int scsw = ((lane & 7) * 16) ^ ((lane >> 3) << 4);

    auto stage = [&](int kt) {
        const char* gA = (const char*)zn + (size_t)(br * 128 + srow) * 256 + kt * 128 + scsw;
        const char* gB = (const char*)zn + (size_t)(bc * 128 + srow) * 256 + kt * 128 + scsw;
        #pragma unroll
        for (int i = 0; i < 4; ++i) {        // +32 rows per issue
            GL2LDS(gA + (size_t)i * 8192, lsA + i * 4096 + w * 1024);
            GL2LDS(gB + (size_t)i * 8192, lsB + i * 4096 + w * 1024);
        }
    };

    f32x4 acc[4][4] = {};

    auto compute = [&]() {
        const int kb = kl * 32;              // this lane-group's 32-B K-chunk
        i32x8 af[4], bv[4];
        #pragma unroll
        for (int mf = 0; mf < 4; ++mf) {
            const int r = wr * 64 + mf * 16 + fr;
            const char* base = (const char*)lsA + r * 128;
            i32x4 lo = *(const i32x4*)(base + ((kb)      ^ swz));
            i32x4 hi = *(const i32x4*)(base + ((kb + 16) ^ swz));
            af[mf] = (i32x8){lo[0], lo[1], lo[2], lo[3], hi[0], hi[1], hi[2], hi[3]};
        }
        #pragma unroll
        for (int nf = 0; nf < 4; ++nf) {
            const int c = wc * 64 + nf * 16 + fr;
            const char* base = (const char*)lsB + c * 128;
            i32x4 lo = *(const i32x4*)(base + ((kb)      ^ swz));
            i32x4 hi = *(const i32x4*)(base + ((kb + 16) ^ swz));
            bv[nf] = (i32x8){lo[0], lo[1], lo[2], lo[3], hi[0], hi[1], hi[2], hi[3]};
        }
        __builtin_amdgcn_s_setprio(1);
        #pragma unroll
        for (int mf = 0; mf < 4; ++mf)
            #pragma unroll
            for (int nf = 0; nf < 4; ++nf)
                acc[mf][nf] = __builtin_amdgcn_mfma_scale_f32_16x16x128_f8f6f4(
                    af[mf], bv[nf], acc[mf][nf], 0, 0, 0, SCALE1, 0, SCALE1);
        __builtin_amdgcn_s_setprio(0);
    };

    stage(0);
    __syncthreads();
    compute();
    __syncthreads();
    stage(1);
    __syncthreads();
    compute();

    // ---- epilogue (R2-proven; C/D layout shape-determined, dtype-independent) ----
    // e = exp((dot-1)/T), diag masked. Row sums -> partials[row][2*bc+wc];
    // off-diag blocks add transpose col sums -> partials[col][2*br+wr].
    const bool offdiag = (br != bc);
    const bool posblk  = (bc == br + 32);
    float colsum[4] = {0.f, 0.f, 0.f, 0.f};

    #pragma unroll
    for (int mf = 0; mf < 4; ++mf) {
        float rs[4] = {0.f, 0.f, 0.f, 0.f};
        const int rowq = br * 128 + wr * 64 + mf * 16 + kl * 4;
        #pragma unroll
        for (int nf = 0; nf < 4; ++nf) {
            const int col = bc * 128 + wc * 64 + nf * 16 + fr;
            f32x4 a = acc[mf][nf];
            #pragma unroll
            for (int j = 0; j < 4; ++j) {
                float e = (rowq + j == col) ? 0.f : __expf((a[j] - 1.0f) * INV_T);
                rs[j]      += e;
                colsum[nf] += e;
                if (posblk && (rowq + j + 4096 == col)) {
                    pos[rowq + j] = a[j];
                    pos[col]      = a[j];
                }
            }
        }
        #pragma unroll
        for (int m = 1; m < 16; m <<= 1) {
            #pragma unroll
            for (int j = 0; j < 4; ++j) rs[j] += __shfl_xor(rs[j], m, 64);
        }
        if (fr == 0) {
            float* p = partials + (size_t)rowq * 128 + bc * 2 + wc;
            p[0]   = rs[0];
            p[128] = rs[1];
            p[256] = rs[2];
            p[384] = rs[3];
        }
    }

    if (offdiag) {
        #pragma unroll
        for (int m = 16; m < 64; m <<= 1) {
            #pragma unroll
            for (int nf = 0; nf < 4; ++nf) colsum[nf] += __shfl_xor(colsum[nf], m, 64);
        }
        if (kl == 0) {
            #pragma unroll
            for (int nf = 0; nf < 4; ++nf) {
                const int col = bc * 128 + wc * 64 + nf * 16 + fr;
                partials[(size_t)col * 128 + br * 2 + wr] = colsum[nf];
            }
        }
    }
}

// ---------- kernel 3: fused loss + deterministic mean (last-block pattern) ----------
__global__ void ntx_loss(const float* __restrict__ partials, const float* __restrict__ pos,
                         float* __restrict__ bsums, u32* __restrict__ counter,
                         float* __restrict__ out)
{
    __shared__ float sm[16];
    __shared__ u32 flag;
    const int tid  = threadIdx.x;
    const int lane = tid & 63;
    const int w    = tid >> 6;       // 0..15

    float a = 0.f;
    #pragma unroll
    for (int i = 0; i < 8; ++i) {
        const int row = blockIdx.x * 128 + w * 8 + i;
        float S = partials[(size_t)row * 128 + lane] + partials[(size_t)row * 128 + 64 + lane];
        #pragma unroll
        for (int m = 1; m < 64; m <<= 1) S += __shfl_xor(S, m, 64);
        if (lane == 0) a += __logf(S) + INV_T - pos[row] * INV_T;
    }
    if (lane == 0) sm[w] = a;
    __syncthreads();

    if (tid == 0) {
        float b = 0.f;
        #pragma unroll
        for (int i = 0; i < 16; ++i) b += sm[i];
        bsums[blockIdx.x] = b;
        __threadfence();                       // release block sum
        u32 old = atomicAdd(counter, 1u);
        flag = (old == 63u) ? 1u : 0u;
    }
    __syncthreads();

    if (flag && w == 0) {                      // last block's wave 0
        __threadfence();                       // acquire all block sums
        float v = bsums[lane];
        #pragma unroll
        for (int m = 1; m < 64; m <<= 1) v += __shfl_xor(v, m, 64);
        if (lane == 0) out[0] = v * (1.0f / (float)N2);
    }
}

extern "C" void kernel_launch(void* const* d_in, const int* in_sizes, int n_in,
                              void* d_out, int out_size, void* d_ws, size_t ws_size,
                              hipStream_t stream)
{
    const float* z1 = (const float*)d_in[0];
    const float* z2 = (const float*)d_in[1];
    float* out = (float*)d_out;

    // workspace layout
    unsigned char* zn       = (unsigned char*)d_ws;                 // 8192*256  = 2 MB
    float*         partials = (float*)((char*)d_ws + (2u << 20));   // 8192*128*4 = 4 MB
    float*         pos      = (float*)((char*)d_ws + (6u << 20));   // 32 KB
    float*         bsums    = pos + N2;                             // 256 B
    u32*           counter  = (u32*)(bsums + 64);                   // 4 B

    hipMemsetAsync(counter, 0, 4, stream);
    ntx_norm<<<N2 / 4, 256, 0, stream>>>(z1, z2, zn);
    ntx_gemm<<<NTRI, 256, 0, stream>>>(zn, partials, pos);
    ntx_loss<<<64, 1024, 0, stream>>>(partials, pos, bsums, counter, out);
}